// Round 13
// baseline (252.080 us; speedup 1.0000x reference)
//
#include <hip/hip_runtime.h>

// ---------------------------------------------------------------------------
// SelfAttention: GN -> 1x1 QKV -> softmax attention (N=4096) -> proj -> +x.
// v18b: identical to v18 (round-12 bench was an infra failure -- container
// died twice; kernel never ran).  v15 frame (4 kernels; cooperative fusion
// abandoned: v16/v17 showed hipLaunchCooperativeKernel never executes under
// this harness).  New vs v15: PV phase via K=128 scaled fp8 MFMA (the v12
// trick applied to PV).  V stored fp8 [b][d][j]; P packed fp8 with
// v_cvt_pk_fp8_f32; per-wave 2KB LDS bounce redistributes P from the
// S-output layout (j=quad*8+[0..8) per 32-j sub-tile) to the PV B-operand
// layout (j=quad*32+[0..32) per 128-j round), XOR-by-i granule swizzle.
// Per 128-j round: 32 S + 32 PV scaled MFMAs (was 32 S + 128 f16 PV);
// barriers 32 -> 8.  K staging/S math identical to v15 (4x 4KB sub-blocks).
// ---------------------------------------------------------------------------

typedef float f32x4 __attribute__((ext_vector_type(4)));
typedef short short8 __attribute__((ext_vector_type(8)));
typedef _Float16 half8 __attribute__((ext_vector_type(8)));
typedef unsigned short ush;
typedef unsigned short ush4 __attribute__((ext_vector_type(4)));
typedef unsigned int uint4t __attribute__((ext_vector_type(4)));
typedef int int8v __attribute__((ext_vector_type(8)));

union V8U {
  uint4t h[2];
  int8v v;
};
union P8U {
  unsigned long long l[4];
  int8v v;
};

__device__ __forceinline__ ush f2bf(float f) {
  unsigned u = __builtin_bit_cast(unsigned, f);
  u = (u + 0x7FFFu + ((u >> 16) & 1u)) >> 16;  // RNE
  return (ush)u;
}
// software f32 -> fp8 e4m3fn (RNE), clamped
__device__ __forceinline__ unsigned f2fp8(float x) {
  unsigned u = __builtin_bit_cast(unsigned, x);
  unsigned s = (u >> 24) & 0x80u;
  unsigned au = u & 0x7fffffffu;
  if (au < 0x3A800000u) return s;              // |x| < 2^-10 -> 0
  if (au >= 0x43E00000u) return s | 0x7Eu;     // >= 448 -> clamp
  int e = (int)(au >> 23) - 127;
  if (e < -6) {                                // subnormal target, grid 2^-9
    float a = __builtin_bit_cast(float, au);
    int m = (int)(a * 512.0f + 0.5f);
    if (m >= 8) return s | 0x08u;
    return s | (unsigned)m;
  }
  unsigned keep = au >> 20, rem = au & 0xFFFFFu;
  keep += (rem > 0x80000u) || ((rem == 0x80000u) && (keep & 1u));
  int ef = (int)(keep >> 3) - 127;
  if (ef >= 8 && ((ef > 8) || ((keep & 7u) == 7u))) return s | 0x7Eu;
  return s | (unsigned)(((ef + 7) << 3) | (int)(keep & 7u));
}
__device__ __forceinline__ void async16(const void* g, void* l) {
  __builtin_amdgcn_global_load_lds(
      (const __attribute__((address_space(1))) unsigned int*)g,
      (__attribute__((address_space(3))) unsigned int*)l, 16, 0, 0);
}

// ---------------------------------------------------------------------------
// Kernel 1: GroupNorm stats -> per-channel scale/shift.  Blocks 0..15:
// wo -> f16 wobh; 16..31: wq -> bf16 wqb; 32..47: wk -> wkb; 48..63: wv -> wvb.
// ---------------------------------------------------------------------------
__global__ __launch_bounds__(256) void gn_stats_kernel(
    const float* __restrict__ x, const float* __restrict__ gamma,
    const float* __restrict__ beta, const float* __restrict__ wo,
    const float* __restrict__ wq, const float* __restrict__ wk,
    const float* __restrict__ wv, float* __restrict__ scale_c,
    float* __restrict__ shift_c, ush* __restrict__ wobh,
    ush* __restrict__ wqb, ush* __restrict__ wkb, ush* __restrict__ wvb) {
  int bg = blockIdx.x;  // b*32 + g
  int b = bg >> 5, g = bg & 31;
  int tid = threadIdx.x;
  if (bg < 64) {  // weight conversions (one-time, piggybacked)
    int m = bg >> 4;
    int v4 = ((bg & 15) * 256 + tid) * 4;
    const float* src = m == 0 ? wo : (m == 1 ? wq : (m == 2 ? wk : wv));
    float4 w4 = *(const float4*)(src + v4);
    ush4 pk;
    if (m == 0) {  // f16 RNE
      pk.x = __builtin_bit_cast(ush, (_Float16)w4.x);
      pk.y = __builtin_bit_cast(ush, (_Float16)w4.y);
      pk.z = __builtin_bit_cast(ush, (_Float16)w4.z);
      pk.w = __builtin_bit_cast(ush, (_Float16)w4.w);
      *(ush4*)(wobh + v4) = pk;
    } else {  // bf16 RNE
      pk.x = f2bf(w4.x); pk.y = f2bf(w4.y);
      pk.z = f2bf(w4.z); pk.w = f2bf(w4.w);
      ush* dst = m == 1 ? wqb : (m == 2 ? wkb : wvb);
      *(ush4*)(dst + v4) = pk;
    }
  }
  const float4* base = (const float4*)(x + (size_t)bg * 16384);
  float s = 0.f, sq = 0.f;
#pragma unroll
  for (int p = 0; p < 16; ++p) {
    float4 v = base[p * 256 + tid];
    s += (v.x + v.y) + (v.z + v.w);
    sq += (v.x * v.x + v.y * v.y) + (v.z * v.z + v.w * v.w);
  }
#pragma unroll
  for (int off = 32; off > 0; off >>= 1) {
    s += __shfl_down(s, off);
    sq += __shfl_down(sq, off);
  }
  __shared__ float rs[4], rq[4], mv[2];
  int w = tid >> 6, lane = tid & 63;
  if (lane == 0) { rs[w] = s; rq[w] = sq; }
  __syncthreads();
  if (tid == 0) {
    float S = (rs[0] + rs[1]) + (rs[2] + rs[3]);
    float Q = (rq[0] + rq[1]) + (rq[2] + rq[3]);
    float mean = S * (1.f / 16384.f);
    float var = Q * (1.f / 16384.f) - mean * mean;
    mv[0] = mean;
    mv[1] = rsqrtf(var + 1e-6f);
  }
  __syncthreads();
  if (tid < 4) {
    int c = (g << 2) + tid;
    float sc = mv[1] * gamma[c];
    scale_c[(b << 7) + c] = sc;
    shift_c[(b << 7) + c] = beta[c] - mv[0] * sc;
  }
}

// ---------------------------------------------------------------------------
// Kernel 2: QKV 1x1 convs via MFMA.  grid 1536 = type(3) x b(8) x itile(64).
// Weights staged into LDS wol[128x136] from pre-converted bf16 copies.
// Outputs: Qt8[b][i][d] fp8 (log2e/sqrt(128) folded), Kt8 fp8,
// Vh8[b][d][j] fp8 (v18: was f16).
// ---------------------------------------------------------------------------
__global__ __launch_bounds__(256) void qkv_kernel(
    const float* __restrict__ x, const float* __restrict__ scale_c,
    const float* __restrict__ shift_c, const ush* __restrict__ wqb,
    const ush* __restrict__ wkb, const ush* __restrict__ wvb,
    const float* __restrict__ bq, const float* __restrict__ bk,
    const float* __restrict__ bv, char* __restrict__ Qt8,
    char* __restrict__ Kt8, char* __restrict__ Vh8) {
  __shared__ __align__(16) ush hs[64 * 136];    // h^T tile, pitch 272B, swizzled
  __shared__ __align__(16) ush wol[128 * 136];  // weight [o][c] bf16
  char* hs8 = (char*)hs;
  int bx = blockIdx.x;
  int type = bx >> 9;  // 0=Q,1=K,2=V
  int rb = bx & 511;
  int b = rb >> 6, i0 = (rb & 63) << 6;
  int tid = threadIdx.x;
  int w = tid >> 6, lane = tid & 63, ln15 = lane & 15, quad = lane >> 4;

  // stage normalized h^T tile: cell = (i, g8) = 4 channels, b64 swizzled write
#pragma unroll
  for (int p = 0; p < 8; ++p) {
    int id = p * 256 + tid;
    int i = id & 63;
    int g8 = id >> 6;
    int c0 = g8 << 2;
    const float* xp = x + (((size_t)((b << 7) + c0)) << 12) + i0 + i;
    ush4 pk4;
#pragma unroll
    for (int e = 0; e < 4; ++e) {
      float h = xp[(size_t)e << 12] * scale_c[(b << 7) + c0 + e] +
                shift_c[(b << 7) + c0 + e];
      pk4[e] = f2bf(h);
    }
    int pg = g8 ^ ((i & 15) << 1);
    *(ush4*)(hs8 + i * 272 + pg * 8) = pk4;
  }
  // stage bf16 weights: 2048 16B-chunks = 128 rows x 16, 8 per thread
  const ush* Wb = type == 0 ? wqb : (type == 1 ? wkb : wvb);
#pragma unroll
  for (int p = 0; p < 8; ++p) {
    int cid = p * 256 + tid;
    int o = cid >> 4, ch = (cid & 15) << 3;
    *(uint4t*)&wol[o * 136 + ch] = *(const uint4t*)(Wb + (o << 7) + ch);
  }
  __syncthreads();

#define HS_FRAG(row, dc) \
  (*(const short8*)(hs8 + (row) * 272 + (((((dc)*4 + quad)) ^ ((row)&15)) << 4)))

  if (type < 2) {
    f32x4 acc[8] = {};
    int hrow = w * 16 + ln15;
#pragma unroll
    for (int dc = 0; dc < 4; ++dc) {
      short8 af = HS_FRAG(hrow, dc);
#pragma unroll
      for (int nb = 0; nb < 8; ++nb) {
        short8 bf = *(const short8*)&wol[(nb * 16 + ln15) * 136 + dc * 32 + quad * 8];
        acc[nb] = __builtin_amdgcn_mfma_f32_16x16x32_bf16(af, bf, acc[nb], 0, 0, 0);
      }
    }
    const float* bias = type == 0 ? bq : bk;
    char* dst8 = type == 0 ? Qt8 : Kt8;
    __syncthreads();  // hs reads done; reuse as bounce [i 64][o 128] pitch 144
#pragma unroll
    for (int nb = 0; nb < 8; ++nb) {
      int o = nb * 16 + ln15;
      float bi = bias[o];
#pragma unroll
      for (int r = 0; r < 4; ++r) {
        float val = acc[nb][r] + bi;
        if (type == 0) val *= 0.12751742f;  // log2(e)/sqrt(128)
        hs8[(w * 16 + quad * 4 + r) * 144 + o] = (char)f2fp8(val);
      }
    }
    __syncthreads();
    int i = tid >> 2, seg = tid & 3;
    uint4 d0 = *(const uint4*)(hs8 + i * 144 + seg * 32);
    uint4 d1 = *(const uint4*)(hs8 + i * 144 + seg * 32 + 16);
    char* drow = dst8 + (((size_t)((b << 12) + i0 + i)) << 7) + seg * 32;
    *(uint4*)drow = d0;
    *(uint4*)(drow + 16) = d1;
  } else {
    f32x4 acc[8] = {};
    int hrow = w * 16 + ln15;
#pragma unroll
    for (int dc = 0; dc < 4; ++dc) {
      short8 bf = HS_FRAG(hrow, dc);
#pragma unroll
      for (int mb = 0; mb < 8; ++mb) {
        short8 af = *(const short8*)&wol[(mb * 16 + ln15) * 136 + dc * 32 + quad * 8];
        acc[mb] = __builtin_amdgcn_mfma_f32_16x16x32_bf16(af, bf, acc[mb], 0, 0, 0);
      }
    }
#pragma unroll
    for (int mb = 0; mb < 8; ++mb) {
#pragma unroll
      for (int r = 0; r < 4; ++r) {
        int o = mb * 16 + quad * 4 + r;
        float val = acc[mb][r] + bv[o];
        Vh8[(((size_t)((b << 7) + o)) << 12) + i0 + w * 16 + ln15] =
            (char)f2fp8(val);
      }
    }
  }
#undef HS_FRAG
}

// ---------------------------------------------------------------------------
// Kernel 3: flash attention, 4-way key split.  grid 512 = b(8) x qt(16) x
// ks(4); 4 waves, 64 q/wave; 8 rounds of 128 keys (4 sub-tiles of 32).
// S: K=128 scaled fp8 MFMA (v12).  PV (v18): K=128 scaled fp8 MFMA; P
// redistributed via per-wave 2KB LDS bounce (XOR-by-i granule swizzle).
// LDS 72KB: K dbuf 2x16KB (4x v15 sub-blocks) + V dbuf 2x16KB fp8 + P 4x2KB.
// ---------------------------------------------------------------------------
__global__ __launch_bounds__(256, 2) void attn_kernel(
    const char* __restrict__ Qt8, const char* __restrict__ Kt8,
    const char* __restrict__ Vh8, ush* __restrict__ po,
    float* __restrict__ lw) {
  __shared__ __align__(16) char smem[73728];
  int bx = blockIdx.x;
  int b = bx & 7, qt = (bx >> 3) & 15, ksid = bx >> 7;
  int tid = threadIdx.x;
  int w = tid >> 6, lane = tid & 63, ln15 = lane & 15, quad = lane >> 4;
  int qbase = (qt << 8) + (w << 6);
  int j0 = ksid << 10;

  // Q fp8 fragments for K=128 MFMA (B-operand: col=i, k=quad*32+[0,32))
  int8v qf[4];
#pragma unroll
  for (int ih = 0; ih < 4; ++ih) {
    const char* qrow =
        Qt8 + (((size_t)((b << 12) + qbase + ih * 16 + ln15)) << 7) + quad * 32;
    V8U u;
    u.h[0] = *(const uint4t*)(qrow);
    u.h[1] = *(const uint4t*)(qrow + 16);
    qf[ih] = u.v;
  }

  // K DMA (v15 mapping, extended to 4 calls x 32 rows per 128-j round)
  int kj = (w << 3) + (lane >> 3);
  int kh = (kj & 3) | (((kj >> 3) & 1) << 2);
  int kg = (lane & 7) ^ kh;
  const char* ksrc = Kt8 + (((size_t)((b << 12) + j0 + kj)) << 7) + (kg << 4);
  // V DMA: rows d = c*32 + w*8 + (lane>>3); granule hash h(d) = (d&3)|((d>>3&1)<<2)
  int vrow = (w << 3) + (lane >> 3);
  int hv_dma = ((lane >> 3) & 3) | ((w & 1) << 2);
  int vgd = (lane & 7) ^ hv_dma;
  const char* vsrc =
      Vh8 + (((size_t)((b << 7) + vrow)) << 12) + j0 + (vgd << 4);

  char* Kb0 = smem;
  char* Kb1 = smem + 16384;
  char* Vb0 = smem + 32768;
  char* Vb1 = smem + 49152;
  char* Pw = smem + 65536 + (w << 11);  // 2KB per wave

  // prologue: stage round 0 into buf 0
#pragma unroll
  for (int c = 0; c < 4; ++c) {
    async16(ksrc + c * 4096, Kb0 + c * 4096 + (w << 10));
    async16(vsrc + (size_t)c * 131072, Vb0 + c * 4096 + (w << 10));
  }
  __syncthreads();

  f32x4 O[4][8] = {};  // O^T: [ih(i)][nb(d-block)]
  float lsum[4] = {0.f, 0.f, 0.f, 0.f};
  const f32x4 SINIT = {-7.2134752f, -7.2134752f, -7.2134752f, -7.2134752f};
  // S sub-tile constants (v15-verified)
  int r0 = ((ln15 >> 2) << 3) + (ln15 & 3), r1 = r0 + 4;
  int hr = (ln15 & 3) | (((ln15 >> 2) & 1) << 2);
  int g0 = ((2 * quad) ^ hr) << 4;
  int g1 = ((2 * quad + 1) ^ hr) << 4;
  // V read hash (row d = nb*16+ln15): h = (ln15&3)|((ln15>>3&1)<<2)
  int hv_r = (ln15 & 3) | (((ln15 >> 3) & 1) << 2);
  int vg0 = ((2 * quad) ^ hv_r) << 4;
  int vg1 = ((2 * quad + 1) ^ hv_r) << 4;

  unsigned pf8a[4][4][2];  // [ih][sub][lo/hi], const-indexed (fully unrolled)

  for (int jt = 0; jt < 8; ++jt) {
    int buf = jt & 1;
    char* Kbc = buf ? Kb1 : Kb0;
    char* Vbc = buf ? Vb1 : Vb0;
    if (jt < 7) {
      ksrc += 16384;
      vsrc += 128;
      char* Kbn = buf ? Kb0 : Kb1;
      char* Vbn = buf ? Vb0 : Vb1;
#pragma unroll
      for (int c = 0; c < 4; ++c) {
        async16(ksrc + c * 4096, Kbn + c * 4096 + (w << 10));
        async16(vsrc + (size_t)c * 131072, Vbn + c * 4096 + (w << 10));
      }
    }

    // ---- S + softmax + fp8 pack, per 32-j sub-tile (v15 S math) ----
#pragma unroll
    for (int s = 0; s < 4; ++s) {
      const char* kb = Kbc + s * 4096;
      V8U ka, kc;
      ka.h[0] = *(const uint4t*)(kb + r0 * 128 + g0);
      ka.h[1] = *(const uint4t*)(kb + r0 * 128 + g1);
      kc.h[0] = *(const uint4t*)(kb + r1 * 128 + g0);
      kc.h[1] = *(const uint4t*)(kb + r1 * 128 + g1);
#pragma unroll
      for (int ih = 0; ih < 4; ++ih) {
        f32x4 S0 = __builtin_amdgcn_mfma_scale_f32_16x16x128_f8f6f4(
            ka.v, qf[ih], SINIT, 0, 0, 0, 0x7F7F7F7F, 0, 0x7F7F7F7F);
        f32x4 S1 = __builtin_amdgcn_mfma_scale_f32_16x16x128_f8f6f4(
            kc.v, qf[ih], SINIT, 0, 0, 0, 0x7F7F7F7F, 0, 0x7F7F7F7F);
        float p0 = __builtin_amdgcn_exp2f(S0[0]);
        float p1 = __builtin_amdgcn_exp2f(S0[1]);
        float p2 = __builtin_amdgcn_exp2f(S0[2]);
        float p3 = __builtin_amdgcn_exp2f(S0[3]);
        float p4 = __builtin_amdgcn_exp2f(S1[0]);
        float p5 = __builtin_amdgcn_exp2f(S1[1]);
        float p6 = __builtin_amdgcn_exp2f(S1[2]);
        float p7 = __builtin_amdgcn_exp2f(S1[3]);
        lsum[ih] += ((p0 + p1) + (p2 + p3)) + ((p4 + p5) + (p6 + p7));
        unsigned lo = (unsigned)__builtin_amdgcn_cvt_pk_fp8_f32(p0, p1, 0, false);
        lo = (unsigned)__builtin_amdgcn_cvt_pk_fp8_f32(p2, p3, (int)lo, true);
        unsigned hi = (unsigned)__builtin_amdgcn_cvt_pk_fp8_f32(p4, p5, 0, false);
        hi = (unsigned)__builtin_amdgcn_cvt_pk_fp8_f32(p6, p7, (int)hi, true);
        pf8a[ih][s][0] = lo;
        pf8a[ih][s][1] = hi;
      }
    }

    // ---- P redistribution (per-wave LDS bounce) + PV, per ih ----
    // write: lane(q,i) sub s holds j = s*32 + q*8 + [0..8) -> granule
    // (s*4+q)^i of row i.  read: lane(t,i) wants j = t*32+[0..32) ->
    // granules (t*4+c)^i.  Same-wave LDS is in-order: no barrier needed.
#pragma unroll
    for (int ih = 0; ih < 4; ++ih) {
#pragma unroll
      for (int s = 0; s < 4; ++s) {
        unsigned long long pr =
            ((unsigned long long)pf8a[ih][s][1] << 32) | pf8a[ih][s][0];
        *(unsigned long long*)(Pw + ln15 * 128 +
                               ((((s << 2) + quad) ^ ln15) << 3)) = pr;
      }
      P8U pu;
#pragma unroll
      for (int c = 0; c < 4; ++c)
        pu.l[c] = *(const unsigned long long*)(
            Pw + ln15 * 128 + ((((quad << 2) + c) ^ ln15) << 3));
      int8v pfv = pu.v;
#pragma unroll
      for (int nb = 0; nb < 8; ++nb) {
        int d = nb * 16 + ln15;
        V8U va;
        va.h[0] = *(const uint4t*)(Vbc + d * 128 + vg0);
        va.h[1] = *(const uint4t*)(Vbc + d * 128 + vg1);
        O[ih][nb] = __builtin_amdgcn_mfma_scale_f32_16x16x128_f8f6f4(
            va.v, pfv, O[ih][nb], 0, 0, 0, 0x7F7F7F7F, 0, 0x7F7F7F7F);
      }
    }
    __syncthreads();  // drains DMA + tile handoff
  }

  // epilogue: unnormalized partial O^T (f16) -> po[ks][b][i][d], sums -> lw
#pragma unroll
  for (int ih = 0; ih < 4; ++ih) {
    float l = lsum[ih];
    l += __shfl_xor(l, 16);
    l += __shfl_xor(l, 32);
    if (quad == 0) lw[(ksid << 15) + (b << 12) + qbase + ih * 16 + ln15] = l;
    int i = qbase + ih * 16 + ln15;
    size_t rowb = (((size_t)((ksid * 8 + b)) << 12) + i) << 7;
#pragma unroll
    for (int nb = 0; nb < 8; ++nb) {
      ush4 pk;
      pk.x = __builtin_bit_cast(ush, (_Float16)O[ih][nb][0]);
      pk.y = __builtin_bit_cast(ush, (_Float16)O[ih][nb][1]);
      pk.z = __builtin_bit_cast(ush, (_Float16)O[ih][nb][2]);
      pk.w = __builtin_bit_cast(ush, (_Float16)O[ih][nb][3]);
      *(ush4*)(po + rowb + nb * 16 + quad * 4) = pk;
    }
  }
}

// ---------------------------------------------------------------------------
// Kernel 4: combine key-split partials + proj + bias + residual.
// grid 1024 = oh(2) x b(8) x itile(64); po combined in packed f16; f16 MFMA.
// ---------------------------------------------------------------------------
__global__ __launch_bounds__(256) void proj_kernel(
    const float* __restrict__ x, const ush* __restrict__ po,
    const float* __restrict__ lw, const ush* __restrict__ wobh,
    const float* __restrict__ bo, float* __restrict__ out) {
  int bx = blockIdx.x;
  int oh = bx & 1;  // o-half: mb base = oh*4
  int bi = bx >> 1;
  int b = bi >> 6, i0 = (bi & 63) << 6;
  int tid = threadIdx.x;
  int w = tid >> 6, lane = tid & 63, ln15 = lane & 15, quad = lane >> 4;
  int i = i0 + w * 16 + ln15;
  float rl = 0.f;
#pragma unroll
  for (int s = 0; s < 4; ++s) rl += lw[(s << 15) + (b << 12) + i];
  _Float16 rh = (_Float16)(1.f / rl);

  f32x4 acc[4] = {};
#pragma unroll
  for (int dc = 0; dc < 4; ++dc) {
    size_t base = ((size_t)i << 7) + dc * 32 + quad * 8;
    half8 vs = *(const half8*)(po + (((size_t)b) << 19) + base);
#pragma unroll
    for (int s = 1; s < 4; ++s)
      vs = vs + *(const half8*)(po + (((size_t)(s * 8 + b)) << 19) + base);
    half8 bfv = vs * rh;
#pragma unroll
    for (int mb = 0; mb < 4; ++mb) {
      half8 af = *(const half8*)&wobh[(((oh * 4 + mb) * 16 + ln15) << 7) +
                                      dc * 32 + quad * 8];
      acc[mb] = __builtin_amdgcn_mfma_f32_16x16x32_f16(af, bfv, acc[mb], 0, 0, 0);
    }
  }
#pragma unroll
  for (int mb = 0; mb < 4; ++mb) {
#pragma unroll
    for (int r = 0; r < 4; ++r) {
      int o = (oh * 4 + mb) * 16 + quad * 4 + r;
      size_t idx = (((size_t)(b << 7) + o) << 12) + i;
      out[idx] = x[idx] + acc[mb][r] + bo[o];
    }
  }
}

// ---------------------------------------------------------------------------
extern "C" void kernel_launch(void* const* d_in, const int* in_sizes, int n_in,
                              void* d_out, int out_size, void* d_ws,
                              size_t ws_size, hipStream_t stream) {
  const float* x = (const float*)d_in[0];
  const float* gamma = (const float*)d_in[1];
  const float* beta = (const float*)d_in[2];
  const float* wq = (const float*)d_in[3];
  const float* bq = (const float*)d_in[4];
  const float* wk = (const float*)d_in[5];
  const float* bk = (const float*)d_in[6];
  const float* wv = (const float*)d_in[7];
  const float* bv = (const float*)d_in[8];
  const float* wo = (const float*)d_in[9];
  const float* bo = (const float*)d_in[10];
  float* out = (float*)d_out;

  const size_t NE = (size_t)8 * 4096 * 128;  // 4M elements
  char* Qt8 = (char*)d_ws;               // fp8 Q^T [b][i][d]   (4MB)
  char* Kt8 = Qt8 + NE;                  // fp8 K^T [b][j][d]   (4MB)
  char* Vh8 = Kt8 + NE;                  // fp8 V [b][d][j]     (4MB)
  ush* po = (ush*)(Vh8 + NE);            // f16 partial O [4][b][i][d] (32MB)
  float* lwp = (float*)(po + 4 * NE);    // f32 partial l [4][b][i] (512KB)
  float* scale_c = lwp + 4 * 32768;
  float* shift_c = scale_c + 1024;
  ush* wobh = (ush*)(shift_c + 1024);    // f16 wo [o][c] (32KB)
  ush* wqb = wobh + 16384;               // bf16 wq [o][c] (32KB)
  ush* wkb = wqb + 16384;                // bf16 wk
  ush* wvb = wkb + 16384;                // bf16 wv

  gn_stats_kernel<<<256, 256, 0, stream>>>(x, gamma, beta, wo, wq, wk, wv,
                                           scale_c, shift_c, wobh, wqb, wkb,
                                           wvb);
  qkv_kernel<<<1536, 256, 0, stream>>>(x, scale_c, shift_c, wqb, wkb, wvb, bq,
                                       bk, bv, Qt8, Kt8, Vh8);
  attn_kernel<<<512, 256, 0, stream>>>(Qt8, Kt8, Vh8, po, lwp);
  proj_kernel<<<1024, 256, 0, stream>>>(x, po, lwp, wobh, bo, out);
}

// Round 14
// 179.234 us; speedup vs baseline: 1.4064x; 1.4064x over previous
//
#include <hip/hip_runtime.h>

// ---------------------------------------------------------------------------
// SelfAttention: GN -> 1x1 QKV -> softmax attention (N=4096) -> proj -> +x.
// v19: revert to v15 frame (best: 186.4us; v18b's K=128-PV spilled ~250MB
// scratch -> 123us attn, abandoned).  One change vs v15: qkv Q/K epilogue
// converts f32->fp8 with HW v_cvt_pk_fp8_f32 (2 cvt + 4 extracts per 4 vals,
// ~8x fewer VALU ops than software f2fp8).  Numerics of the HW cvt were
// correctness-proven by v18b (whole P path through it, absmax unchanged).
// attn = v12 structure (61us, K=128 scaled MFMA S-phase, f16 po).
// ---------------------------------------------------------------------------

typedef float f32x4 __attribute__((ext_vector_type(4)));
typedef short short8 __attribute__((ext_vector_type(8)));
typedef _Float16 half8 __attribute__((ext_vector_type(8)));
typedef _Float16 half2t __attribute__((ext_vector_type(2)));
typedef unsigned short ush;
typedef unsigned short ush4 __attribute__((ext_vector_type(4)));
typedef unsigned int uint4t __attribute__((ext_vector_type(4)));
typedef int int8v __attribute__((ext_vector_type(8)));

union V8U {
  uint4t h[2];
  int8v v;
};

__device__ __forceinline__ ush f2bf(float f) {
  unsigned u = __builtin_bit_cast(unsigned, f);
  u = (u + 0x7FFFu + ((u >> 16) & 1u)) >> 16;  // RNE
  return (ush)u;
}
__device__ __forceinline__ float bf2f(ush v) {
  unsigned u = ((unsigned)v) << 16;
  return __builtin_bit_cast(float, u);
}
// software f32 -> fp8 e4m3fn (RNE), clamped (kept for V path reference)
__device__ __forceinline__ unsigned f2fp8(float x) {
  unsigned u = __builtin_bit_cast(unsigned, x);
  unsigned s = (u >> 24) & 0x80u;
  unsigned au = u & 0x7fffffffu;
  if (au < 0x3A800000u) return s;              // |x| < 2^-10 -> 0
  if (au >= 0x43E00000u) return s | 0x7Eu;     // >= 448 -> clamp
  int e = (int)(au >> 23) - 127;
  if (e < -6) {                                // subnormal target, grid 2^-9
    float a = __builtin_bit_cast(float, au);
    int m = (int)(a * 512.0f + 0.5f);
    if (m >= 8) return s | 0x08u;
    return s | (unsigned)m;
  }
  unsigned keep = au >> 20, rem = au & 0xFFFFFu;
  keep += (rem > 0x80000u) || ((rem == 0x80000u) && (keep & 1u));
  int ef = (int)(keep >> 3) - 127;
  if (ef >= 8 && ((ef > 8) || ((keep & 7u) == 7u))) return s | 0x7Eu;
  return s | (unsigned)(((ef + 7) << 3) | (int)(keep & 7u));
}
__device__ __forceinline__ void async16(const void* g, void* l) {
  __builtin_amdgcn_global_load_lds(
      (const __attribute__((address_space(1))) unsigned int*)g,
      (__attribute__((address_space(3))) unsigned int*)l, 16, 0, 0);
}

// ---------------------------------------------------------------------------
// Kernel 1: GroupNorm stats -> per-channel scale/shift.  Blocks 0..15:
// wo -> f16 wobh; 16..31: wq -> bf16 wqb; 32..47: wk -> wkb; 48..63: wv -> wvb.
// ---------------------------------------------------------------------------
__global__ __launch_bounds__(256) void gn_stats_kernel(
    const float* __restrict__ x, const float* __restrict__ gamma,
    const float* __restrict__ beta, const float* __restrict__ wo,
    const float* __restrict__ wq, const float* __restrict__ wk,
    const float* __restrict__ wv, float* __restrict__ scale_c,
    float* __restrict__ shift_c, ush* __restrict__ wobh,
    ush* __restrict__ wqb, ush* __restrict__ wkb, ush* __restrict__ wvb) {
  int bg = blockIdx.x;  // b*32 + g
  int b = bg >> 5, g = bg & 31;
  int tid = threadIdx.x;
  if (bg < 64) {  // weight conversions (one-time, piggybacked)
    int m = bg >> 4;
    int v4 = ((bg & 15) * 256 + tid) * 4;
    const float* src = m == 0 ? wo : (m == 1 ? wq : (m == 2 ? wk : wv));
    float4 w4 = *(const float4*)(src + v4);
    ush4 pk;
    if (m == 0) {  // f16 RNE
      pk.x = __builtin_bit_cast(ush, (_Float16)w4.x);
      pk.y = __builtin_bit_cast(ush, (_Float16)w4.y);
      pk.z = __builtin_bit_cast(ush, (_Float16)w4.z);
      pk.w = __builtin_bit_cast(ush, (_Float16)w4.w);
      *(ush4*)(wobh + v4) = pk;
    } else {  // bf16 RNE
      pk.x = f2bf(w4.x); pk.y = f2bf(w4.y);
      pk.z = f2bf(w4.z); pk.w = f2bf(w4.w);
      ush* dst = m == 1 ? wqb : (m == 2 ? wkb : wvb);
      *(ush4*)(dst + v4) = pk;
    }
  }
  const float4* base = (const float4*)(x + (size_t)bg * 16384);
  float s = 0.f, sq = 0.f;
#pragma unroll
  for (int p = 0; p < 16; ++p) {
    float4 v = base[p * 256 + tid];
    s += (v.x + v.y) + (v.z + v.w);
    sq += (v.x * v.x + v.y * v.y) + (v.z * v.z + v.w * v.w);
  }
#pragma unroll
  for (int off = 32; off > 0; off >>= 1) {
    s += __shfl_down(s, off);
    sq += __shfl_down(sq, off);
  }
  __shared__ float rs[4], rq[4], mv[2];
  int w = tid >> 6, lane = tid & 63;
  if (lane == 0) { rs[w] = s; rq[w] = sq; }
  __syncthreads();
  if (tid == 0) {
    float S = (rs[0] + rs[1]) + (rs[2] + rs[3]);
    float Q = (rq[0] + rq[1]) + (rq[2] + rq[3]);
    float mean = S * (1.f / 16384.f);
    float var = Q * (1.f / 16384.f) - mean * mean;
    mv[0] = mean;
    mv[1] = rsqrtf(var + 1e-6f);
  }
  __syncthreads();
  if (tid < 4) {
    int c = (g << 2) + tid;
    float sc = mv[1] * gamma[c];
    scale_c[(b << 7) + c] = sc;
    shift_c[(b << 7) + c] = beta[c] - mv[0] * sc;
  }
}

// ---------------------------------------------------------------------------
// Kernel 2: QKV 1x1 convs via MFMA.  grid 1536 = type(3) x b(8) x itile(64).
// Weights staged into LDS wol[128x136] from pre-converted bf16 copies.
// v19: Q/K fp8 conversion via HW v_cvt_pk_fp8_f32 (numerics proven v18b).
// Outputs: Qt8[b][i][d] fp8 (log2e/sqrt(128) folded), Kt8 fp8, Vh f16.
// ---------------------------------------------------------------------------
__global__ __launch_bounds__(256) void qkv_kernel(
    const float* __restrict__ x, const float* __restrict__ scale_c,
    const float* __restrict__ shift_c, const ush* __restrict__ wqb,
    const ush* __restrict__ wkb, const ush* __restrict__ wvb,
    const float* __restrict__ bq, const float* __restrict__ bk,
    const float* __restrict__ bv, char* __restrict__ Qt8,
    char* __restrict__ Kt8, _Float16* __restrict__ Vh) {
  __shared__ __align__(16) ush hs[64 * 136];    // h^T tile, pitch 272B, swizzled
  __shared__ __align__(16) ush wol[128 * 136];  // weight [o][c] bf16
  char* hs8 = (char*)hs;
  int bx = blockIdx.x;
  int type = bx >> 9;  // 0=Q,1=K,2=V
  int rb = bx & 511;
  int b = rb >> 6, i0 = (rb & 63) << 6;
  int tid = threadIdx.x;
  int w = tid >> 6, lane = tid & 63, ln15 = lane & 15, quad = lane >> 4;

  // stage normalized h^T tile: cell = (i, g8) = 4 channels, b64 swizzled write
#pragma unroll
  for (int p = 0; p < 8; ++p) {
    int id = p * 256 + tid;
    int i = id & 63;
    int g8 = id >> 6;
    int c0 = g8 << 2;
    const float* xp = x + (((size_t)((b << 7) + c0)) << 12) + i0 + i;
    ush4 pk4;
#pragma unroll
    for (int e = 0; e < 4; ++e) {
      float h = xp[(size_t)e << 12] * scale_c[(b << 7) + c0 + e] +
                shift_c[(b << 7) + c0 + e];
      pk4[e] = f2bf(h);
    }
    int pg = g8 ^ ((i & 15) << 1);
    *(ush4*)(hs8 + i * 272 + pg * 8) = pk4;
  }
  // stage bf16 weights: 2048 16B-chunks = 128 rows x 16, 8 per thread
  const ush* Wb = type == 0 ? wqb : (type == 1 ? wkb : wvb);
#pragma unroll
  for (int p = 0; p < 8; ++p) {
    int cid = p * 256 + tid;
    int o = cid >> 4, ch = (cid & 15) << 3;
    *(uint4t*)&wol[o * 136 + ch] = *(const uint4t*)(Wb + (o << 7) + ch);
  }
  __syncthreads();

#define HS_FRAG(row, dc) \
  (*(const short8*)(hs8 + (row) * 272 + (((((dc)*4 + quad)) ^ ((row)&15)) << 4)))

  if (type < 2) {
    f32x4 acc[8] = {};
    int hrow = w * 16 + ln15;
#pragma unroll
    for (int dc = 0; dc < 4; ++dc) {
      short8 af = HS_FRAG(hrow, dc);
#pragma unroll
      for (int nb = 0; nb < 8; ++nb) {
        short8 bf = *(const short8*)&wol[(nb * 16 + ln15) * 136 + dc * 32 + quad * 8];
        acc[nb] = __builtin_amdgcn_mfma_f32_16x16x32_bf16(af, bf, acc[nb], 0, 0, 0);
      }
    }
    const float* bias = type == 0 ? bq : bk;
    char* dst8 = type == 0 ? Qt8 : Kt8;
    __syncthreads();  // hs reads done; reuse as bounce [i 64][o 128] pitch 144
#pragma unroll
    for (int nb = 0; nb < 8; ++nb) {
      int o = nb * 16 + ln15;
      float bi = bias[o];
      float v0 = acc[nb][0] + bi, v1 = acc[nb][1] + bi;
      float v2 = acc[nb][2] + bi, v3 = acc[nb][3] + bi;
      if (type == 0) {
        v0 *= 0.12751742f; v1 *= 0.12751742f;  // log2(e)/sqrt(128)
        v2 *= 0.12751742f; v3 *= 0.12751742f;
      }
      unsigned u = (unsigned)__builtin_amdgcn_cvt_pk_fp8_f32(v0, v1, 0, false);
      u = (unsigned)__builtin_amdgcn_cvt_pk_fp8_f32(v2, v3, (int)u, true);
      int rbase = (w * 16 + quad * 4) * 144 + o;
      hs8[rbase] = (char)(u & 0xffu);
      hs8[rbase + 144] = (char)((u >> 8) & 0xffu);
      hs8[rbase + 288] = (char)((u >> 16) & 0xffu);
      hs8[rbase + 432] = (char)(u >> 24);
    }
    __syncthreads();
    int i = tid >> 2, seg = tid & 3;
    uint4 d0 = *(const uint4*)(hs8 + i * 144 + seg * 32);
    uint4 d1 = *(const uint4*)(hs8 + i * 144 + seg * 32 + 16);
    char* drow = dst8 + (((size_t)((b << 12) + i0 + i)) << 7) + seg * 32;
    *(uint4*)drow = d0;
    *(uint4*)(drow + 16) = d1;
  } else {
    f32x4 acc[8] = {};
    int hrow = w * 16 + ln15;
#pragma unroll
    for (int dc = 0; dc < 4; ++dc) {
      short8 bf = HS_FRAG(hrow, dc);
#pragma unroll
      for (int mb = 0; mb < 8; ++mb) {
        short8 af = *(const short8*)&wol[(mb * 16 + ln15) * 136 + dc * 32 + quad * 8];
        acc[mb] = __builtin_amdgcn_mfma_f32_16x16x32_bf16(af, bf, acc[mb], 0, 0, 0);
      }
    }
#pragma unroll
    for (int mb = 0; mb < 8; ++mb) {
#pragma unroll
      for (int r = 0; r < 4; ++r) {
        int o = mb * 16 + quad * 4 + r;
        float val = acc[mb][r] + bv[o];
        Vh[(((size_t)((b << 7) + o)) << 12) + i0 + w * 16 + ln15] = (_Float16)val;
      }
    }
  }
#undef HS_FRAG
}

// ---------------------------------------------------------------------------
// Kernel 3: flash attention, 4-way key split.  grid 512 = b(8) x qt(16) x
// ks(4); 4 waves, 64 q/wave; 32 key-tiles of 32.  v12 structure (K=128
// scaled MFMA S-phase, 61us); epilogue packs O partials as f16.
// ---------------------------------------------------------------------------
__global__ __launch_bounds__(256, 2) void attn_kernel(
    const char* __restrict__ Qt8, const char* __restrict__ Kt8,
    const _Float16* __restrict__ Vh, ush* __restrict__ po,
    float* __restrict__ lw) {
  __shared__ __align__(16) char ksb[2][4096];      // [j32][d128] fp8 swizzled
  __shared__ __align__(16) _Float16 vsb[2][4096];  // [d128][j32] f16 swizzled
  int bx = blockIdx.x;
  int b = bx & 7, qt = (bx >> 3) & 15, ksid = bx >> 7;
  int tid = threadIdx.x;
  int w = tid >> 6, lane = tid & 63, ln15 = lane & 15, quad = lane >> 4;
  int qbase = (qt << 8) + (w << 6);
  int j0 = ksid << 10;

  // Q fp8 fragments for K=128 MFMA (B-operand: col=i, k=quad*32+[0,32))
  int8v qf[4];
#pragma unroll
  for (int ih = 0; ih < 4; ++ih) {
    const char* qrow =
        Qt8 + (((size_t)((b << 12) + qbase + ih * 16 + ln15)) << 7) + quad * 32;
    V8U u;
    u.h[0] = *(const uint4t*)(qrow);
    u.h[1] = *(const uint4t*)(qrow + 16);
    qf[ih] = u.v;
  }

  // DMA source mappings (swizzle folded into per-lane source address)
  int kj = (w << 3) + (lane >> 3);
  int kh = (kj & 3) | (((kj >> 3) & 1) << 2);
  int kg = (lane & 7) ^ kh;
  const char* ksrc = Kt8 + (((size_t)((b << 12) + j0 + kj)) << 7) + (kg << 4);
  int d0r = (w << 5) + (lane >> 2);
  int d1r = d0r + 16;
  int vg0 = (lane & 3) ^ (((d0r >> 1) + (d0r >> 3)) & 3);
  int vg1 = (lane & 3) ^ (((d1r >> 1) + (d1r >> 3)) & 3);
  const _Float16* vsrc0 =
      Vh + (((size_t)((b << 7) + d0r)) << 12) + j0 + (vg0 << 3);
  const _Float16* vsrc1 =
      Vh + (((size_t)((b << 7) + d1r)) << 12) + j0 + (vg1 << 3);
  char* kdA = &ksb[0][0] + (w << 10);
  char* kdB = &ksb[1][0] + (w << 10);
  char* vdA0 = (char*)&vsb[0][0] + ((w * 2 + 0) << 10);
  char* vdA1 = (char*)&vsb[0][0] + ((w * 2 + 1) << 10);
  char* vdB0 = (char*)&vsb[1][0] + ((w * 2 + 0) << 10);
  char* vdB1 = (char*)&vsb[1][0] + ((w * 2 + 1) << 10);

  // stage tile 0 into buf 0
  async16(ksrc, kdA);
  async16(vsrc0, vdA0);
  async16(vsrc1, vdA1);
  __syncthreads();

  f32x4 O[4][8] = {};  // O^T: [ih(i)][nb(d-block)]
  float lsum[4] = {0.f, 0.f, 0.f, 0.f};
  const f32x4 SINIT = {-7.2134752f, -7.2134752f, -7.2134752f, -7.2134752f};
  // permuted K rows for the S A-operand + their (shared) group hash
  int r0 = ((ln15 >> 2) << 3) + (ln15 & 3), r1 = r0 + 4;
  int hr = (ln15 & 3) | (((ln15 >> 2) & 1) << 2);
  // swizzled byte offsets of the two 16B k-groups this lane needs (k=quad*32)
  int g0 = ((2 * quad) ^ hr) << 4;
  int g1 = ((2 * quad + 1) ^ hr) << 4;

  for (int jt = 0; jt < 32; ++jt) {
    int buf = jt & 1;
    if (jt + 1 < 32) {
      ksrc += 4096;
      vsrc0 += 32;
      vsrc1 += 32;
      if (buf == 0) {
        async16(ksrc, kdB);
        async16(vsrc0, vdB0);
        async16(vsrc1, vdB1);
      } else {
        async16(ksrc, kdA);
        async16(vsrc0, vdA0);
        async16(vsrc1, vdA1);
      }
    }
    const char* kb = &ksb[buf][0];
    const char* vb = (const char*)&vsb[buf][0];

    // S^T = K(permuted rows) . Q  -- one K=128 scaled MFMA per (ih, row-tile)
    V8U ka, kc;
    ka.h[0] = *(const uint4t*)(kb + r0 * 128 + g0);
    ka.h[1] = *(const uint4t*)(kb + r0 * 128 + g1);
    kc.h[0] = *(const uint4t*)(kb + r1 * 128 + g0);
    kc.h[1] = *(const uint4t*)(kb + r1 * 128 + g1);
    f32x4 S[4][2];
#pragma unroll
    for (int ih = 0; ih < 4; ++ih) {
      S[ih][0] = __builtin_amdgcn_mfma_scale_f32_16x16x128_f8f6f4(
          ka.v, qf[ih], SINIT, 0, 0, 0, 0x7F7F7F7F, 0, 0x7F7F7F7F);
      S[ih][1] = __builtin_amdgcn_mfma_scale_f32_16x16x128_f8f6f4(
          kc.v, qf[ih], SINIT, 0, 0, 0, 0x7F7F7F7F, 0, 0x7F7F7F7F);
    }

    // exp2 -> f16 via packed cvt words; tile0 regs = k 0..3, tile1 = k 4..7
    half8 pf[4];
#pragma unroll
    for (int ih = 0; ih < 4; ++ih) {
      float p0 = __builtin_amdgcn_exp2f(S[ih][0][0]);
      float p1 = __builtin_amdgcn_exp2f(S[ih][0][1]);
      float p2 = __builtin_amdgcn_exp2f(S[ih][0][2]);
      float p3 = __builtin_amdgcn_exp2f(S[ih][0][3]);
      float p4 = __builtin_amdgcn_exp2f(S[ih][1][0]);
      float p5 = __builtin_amdgcn_exp2f(S[ih][1][1]);
      float p6 = __builtin_amdgcn_exp2f(S[ih][1][2]);
      float p7 = __builtin_amdgcn_exp2f(S[ih][1][3]);
      lsum[ih] += ((p0 + p1) + (p2 + p3)) + ((p4 + p5) + (p6 + p7));
      uint4t pw;
      pw.x = __builtin_bit_cast(unsigned, __builtin_amdgcn_cvt_pkrtz(p0, p1));
      pw.y = __builtin_bit_cast(unsigned, __builtin_amdgcn_cvt_pkrtz(p2, p3));
      pw.z = __builtin_bit_cast(unsigned, __builtin_amdgcn_cvt_pkrtz(p4, p5));
      pw.w = __builtin_bit_cast(unsigned, __builtin_amdgcn_cvt_pkrtz(p6, p7));
      pf[ih] = __builtin_bit_cast(half8, pw);
    }
    // O^T += V . P   (f16 K=32 MFMA, 32/iter; V frag = one b128)
#pragma unroll
    for (int nb = 0; nb < 8; ++nb) {
      int d = nb * 16 + ln15;
      int sd = ((d >> 1) + (d >> 3)) & 3;
      half8 vf = *(const half8*)(vb + d * 64 + ((quad ^ sd) << 4));
#pragma unroll
      for (int ih = 0; ih < 4; ++ih)
        O[ih][nb] = __builtin_amdgcn_mfma_f32_16x16x32_f16(vf, pf[ih], O[ih][nb], 0, 0, 0);
    }
    __syncthreads();  // drains DMA + tile handoff
  }

  // epilogue: unnormalized partial O^T (f16) -> po[ks][b][i][d], sums -> lw
#pragma unroll
  for (int ih = 0; ih < 4; ++ih) {
    float l = lsum[ih];
    l += __shfl_xor(l, 16);
    l += __shfl_xor(l, 32);
    if (quad == 0) lw[(ksid << 15) + (b << 12) + qbase + ih * 16 + ln15] = l;
    int i = qbase + ih * 16 + ln15;
    size_t rowb = (((size_t)((ksid * 8 + b)) << 12) + i) << 7;
#pragma unroll
    for (int nb = 0; nb < 8; ++nb) {
      ush4 pk;
      pk.x = __builtin_bit_cast(ush, (_Float16)O[ih][nb][0]);
      pk.y = __builtin_bit_cast(ush, (_Float16)O[ih][nb][1]);
      pk.z = __builtin_bit_cast(ush, (_Float16)O[ih][nb][2]);
      pk.w = __builtin_bit_cast(ush, (_Float16)O[ih][nb][3]);
      *(ush4*)(po + rowb + nb * 16 + quad * 4) = pk;
    }
  }
}

// ---------------------------------------------------------------------------
// Kernel 4: combine key-split partials + proj + bias + residual.
// grid 1024 = oh(2) x b(8) x itile(64); po combined in packed f16; f16 MFMA.
// ---------------------------------------------------------------------------
__global__ __launch_bounds__(256) void proj_kernel(
    const float* __restrict__ x, const ush* __restrict__ po,
    const float* __restrict__ lw, const ush* __restrict__ wobh,
    const float* __restrict__ bo, float* __restrict__ out) {
  int bx = blockIdx.x;
  int oh = bx & 1;  // o-half: mb base = oh*4
  int bi = bx >> 1;
  int b = bi >> 6, i0 = (bi & 63) << 6;
  int tid = threadIdx.x;
  int w = tid >> 6, lane = tid & 63, ln15 = lane & 15, quad = lane >> 4;
  int i = i0 + w * 16 + ln15;
  float rl = 0.f;
#pragma unroll
  for (int s = 0; s < 4; ++s) rl += lw[(s << 15) + (b << 12) + i];
  _Float16 rh = (_Float16)(1.f / rl);

  f32x4 acc[4] = {};
#pragma unroll
  for (int dc = 0; dc < 4; ++dc) {
    size_t base = ((size_t)i << 7) + dc * 32 + quad * 8;
    half8 vs = *(const half8*)(po + (((size_t)b) << 19) + base);
#pragma unroll
    for (int s = 1; s < 4; ++s)
      vs = vs + *(const half8*)(po + (((size_t)(s * 8 + b)) << 19) + base);
    half8 bfv = vs * rh;
#pragma unroll
    for (int mb = 0; mb < 4; ++mb) {
      half8 af = *(const half8*)&wobh[(((oh * 4 + mb) * 16 + ln15) << 7) +
                                      dc * 32 + quad * 8];
      acc[mb] = __builtin_amdgcn_mfma_f32_16x16x32_f16(af, bfv, acc[mb], 0, 0, 0);
    }
  }
#pragma unroll
  for (int mb = 0; mb < 4; ++mb) {
#pragma unroll
    for (int r = 0; r < 4; ++r) {
      int o = (oh * 4 + mb) * 16 + quad * 4 + r;
      size_t idx = (((size_t)(b << 7) + o) << 12) + i;
      out[idx] = x[idx] + acc[mb][r] + bo[o];
    }
  }
}

// ---------------------------------------------------------------------------
extern "C" void kernel_launch(void* const* d_in, const int* in_sizes, int n_in,
                              void* d_out, int out_size, void* d_ws,
                              size_t ws_size, hipStream_t stream) {
  const float* x = (const float*)d_in[0];
  const float* gamma = (const float*)d_in[1];
  const float* beta = (const float*)d_in[2];
  const float* wq = (const float*)d_in[3];
  const float* bq = (const float*)d_in[4];
  const float* wk = (const float*)d_in[5];
  const float* bk = (const float*)d_in[6];
  const float* wv = (const float*)d_in[7];
  const float* bv = (const float*)d_in[8];
  const float* wo = (const float*)d_in[9];
  const float* bo = (const float*)d_in[10];
  float* out = (float*)d_out;

  const size_t NE = (size_t)8 * 4096 * 128;  // 4M elements
  char* Qt8 = (char*)d_ws;               // fp8 Q^T [b][i][d]   (4MB)
  char* Kt8 = Qt8 + NE;                  // fp8 K^T [b][j][d]   (4MB)
  _Float16* Vh = (_Float16*)(Kt8 + NE);  // f16 V [b][d][j]     (8MB)
  ush* po = (ush*)(Vh + NE);             // f16 partial O [4][b][i][d] (32MB)
  float* lwp = (float*)(po + 4 * NE);    // f32 partial l [4][b][i] (512KB)
  float* scale_c = lwp + 4 * 32768;
  float* shift_c = scale_c + 1024;
  ush* wobh = (ush*)(shift_c + 1024);    // f16 wo [o][c] (32KB)
  ush* wqb = wobh + 16384;               // bf16 wq [o][c] (32KB)
  ush* wkb = wqb + 16384;                // bf16 wk
  ush* wvb = wkb + 16384;                // bf16 wv

  gn_stats_kernel<<<256, 256, 0, stream>>>(x, gamma, beta, wo, wq, wk, wv,
                                           scale_c, shift_c, wobh, wqb, wkb,
                                           wvb);
  qkv_kernel<<<1536, 256, 0, stream>>>(x, scale_c, shift_c, wqb, wkb, wvb, bq,
                                       bk, bv, Qt8, Kt8, Vh);
  attn_kernel<<<512, 256, 0, stream>>>(Qt8, Kt8, Vh, po, lwp);
  proj_kernel<<<1024, 256, 0, stream>>>(x, po, lwp, wobh, bo, out);
}

// Round 15
// 178.366 us; speedup vs baseline: 1.4133x; 1.0049x over previous
//
#include <hip/hip_runtime.h>

// ---------------------------------------------------------------------------
// SelfAttention: GN -> 1x1 QKV -> softmax attention (N=4096) -> proj -> +x.
// v20: two work-removal sweeps on the v19 frame (179.2us).
// (1) qkv h-path all-f16: gn emits wq/wk/wv as f16, hs staged via HW
//     cvt_pkrtz (kills 32 software f2bf/thread), MFMA f16 (same layout).
// (2) po stored fp8: attn epilogue packs O with cvt_pk_fp8_f32 (v18b-proven
//     encode), proj decodes with cvt_pk_f32_fp8; po round-trip 96->48MB.
//     Overflow-safe: unnormalized O ~15 << 448 (softmax shift -5*log2e).
// attn loop = v12 structure, untouched (61-62us anchor).
// ---------------------------------------------------------------------------

typedef float f32x4 __attribute__((ext_vector_type(4)));
typedef float f32x2 __attribute__((ext_vector_type(2)));
typedef short short8 __attribute__((ext_vector_type(8)));
typedef _Float16 half8 __attribute__((ext_vector_type(8)));
typedef _Float16 half2t __attribute__((ext_vector_type(2)));
typedef unsigned short ush;
typedef unsigned short ush4 __attribute__((ext_vector_type(4)));
typedef unsigned int uint4t __attribute__((ext_vector_type(4)));
typedef int int8v __attribute__((ext_vector_type(8)));
typedef unsigned long long ull;

union V8U {
  uint4t h[2];
  int8v v;
};

__device__ __forceinline__ ush f2bf(float f) {
  unsigned u = __builtin_bit_cast(unsigned, f);
  u = (u + 0x7FFFu + ((u >> 16) & 1u)) >> 16;  // RNE (unused hot-path; kept)
  return (ush)u;
}
__device__ __forceinline__ void async16(const void* g, void* l) {
  __builtin_amdgcn_global_load_lds(
      (const __attribute__((address_space(1))) unsigned int*)g,
      (__attribute__((address_space(3))) unsigned int*)l, 16, 0, 0);
}

// ---------------------------------------------------------------------------
// Kernel 1: GroupNorm stats -> per-channel scale/shift.  Blocks 0..63 also
// convert weights: all four (wo,wq,wk,wv) -> f16.
// ---------------------------------------------------------------------------
__global__ __launch_bounds__(256) void gn_stats_kernel(
    const float* __restrict__ x, const float* __restrict__ gamma,
    const float* __restrict__ beta, const float* __restrict__ wo,
    const float* __restrict__ wq, const float* __restrict__ wk,
    const float* __restrict__ wv, float* __restrict__ scale_c,
    float* __restrict__ shift_c, ush* __restrict__ wobh,
    ush* __restrict__ wqh, ush* __restrict__ wkh, ush* __restrict__ wvh) {
  int bg = blockIdx.x;  // b*32 + g
  int b = bg >> 5, g = bg & 31;
  int tid = threadIdx.x;
  if (bg < 64) {  // weight conversions (one-time, piggybacked), all f16 RNE
    int m = bg >> 4;
    int v4 = ((bg & 15) * 256 + tid) * 4;
    const float* src = m == 0 ? wo : (m == 1 ? wq : (m == 2 ? wk : wv));
    float4 w4 = *(const float4*)(src + v4);
    ush4 pk;
    pk.x = __builtin_bit_cast(ush, (_Float16)w4.x);
    pk.y = __builtin_bit_cast(ush, (_Float16)w4.y);
    pk.z = __builtin_bit_cast(ush, (_Float16)w4.z);
    pk.w = __builtin_bit_cast(ush, (_Float16)w4.w);
    ush* dst = m == 0 ? wobh : (m == 1 ? wqh : (m == 2 ? wkh : wvh));
    *(ush4*)(dst + v4) = pk;
  }
  const float4* base = (const float4*)(x + (size_t)bg * 16384);
  float s = 0.f, sq = 0.f;
#pragma unroll
  for (int p = 0; p < 16; ++p) {
    float4 v = base[p * 256 + tid];
    s += (v.x + v.y) + (v.z + v.w);
    sq += (v.x * v.x + v.y * v.y) + (v.z * v.z + v.w * v.w);
  }
#pragma unroll
  for (int off = 32; off > 0; off >>= 1) {
    s += __shfl_down(s, off);
    sq += __shfl_down(sq, off);
  }
  __shared__ float rs[4], rq[4], mv[2];
  int w = tid >> 6, lane = tid & 63;
  if (lane == 0) { rs[w] = s; rq[w] = sq; }
  __syncthreads();
  if (tid == 0) {
    float S = (rs[0] + rs[1]) + (rs[2] + rs[3]);
    float Q = (rq[0] + rq[1]) + (rq[2] + rq[3]);
    float mean = S * (1.f / 16384.f);
    float var = Q * (1.f / 16384.f) - mean * mean;
    mv[0] = mean;
    mv[1] = rsqrtf(var + 1e-6f);
  }
  __syncthreads();
  if (tid < 4) {
    int c = (g << 2) + tid;
    float sc = mv[1] * gamma[c];
    scale_c[(b << 7) + c] = sc;
    shift_c[(b << 7) + c] = beta[c] - mv[0] * sc;
  }
}

// ---------------------------------------------------------------------------
// Kernel 2: QKV 1x1 convs via MFMA.  grid 1536 = type(3) x b(8) x itile(64).
// v20: all-f16 h path -- hs staged via HW cvt_pkrtz, weights f16 from L2,
// f16 MFMA.  Q/K fp8 epilogue via HW cvt_pk_fp8_f32 (v19).
// Outputs: Qt8[b][i][d] fp8 (log2e/sqrt(128) folded), Kt8 fp8, Vh f16.
// ---------------------------------------------------------------------------
__global__ __launch_bounds__(256) void qkv_kernel(
    const float* __restrict__ x, const float* __restrict__ scale_c,
    const float* __restrict__ shift_c, const ush* __restrict__ wqh,
    const ush* __restrict__ wkh, const ush* __restrict__ wvh,
    const float* __restrict__ bq, const float* __restrict__ bk,
    const float* __restrict__ bv, char* __restrict__ Qt8,
    char* __restrict__ Kt8, _Float16* __restrict__ Vh) {
  __shared__ __align__(16) ush hs[64 * 136];    // h^T tile f16, pitch 272B, swz
  __shared__ __align__(16) ush wol[128 * 136];  // weight [o][c] f16
  char* hs8 = (char*)hs;
  int bx = blockIdx.x;
  int type = bx >> 9;  // 0=Q,1=K,2=V
  int rb = bx & 511;
  int b = rb >> 6, i0 = (rb & 63) << 6;
  int tid = threadIdx.x;
  int w = tid >> 6, lane = tid & 63, ln15 = lane & 15, quad = lane >> 4;

  // stage normalized h^T tile (f16 via packed HW cvt), b64 swizzled write
#pragma unroll
  for (int p = 0; p < 8; ++p) {
    int id = p * 256 + tid;
    int i = id & 63;
    int g8 = id >> 6;
    int c0 = g8 << 2;
    const float* xp = x + (((size_t)((b << 7) + c0)) << 12) + i0 + i;
    float h0 = xp[0] * scale_c[(b << 7) + c0] + shift_c[(b << 7) + c0];
    float h1 = xp[(size_t)1 << 12] * scale_c[(b << 7) + c0 + 1] +
               shift_c[(b << 7) + c0 + 1];
    float h2 = xp[(size_t)2 << 12] * scale_c[(b << 7) + c0 + 2] +
               shift_c[(b << 7) + c0 + 2];
    float h3 = xp[(size_t)3 << 12] * scale_c[(b << 7) + c0 + 3] +
               shift_c[(b << 7) + c0 + 3];
    uint2 pk2;
    pk2.x = __builtin_bit_cast(unsigned, __builtin_amdgcn_cvt_pkrtz(h0, h1));
    pk2.y = __builtin_bit_cast(unsigned, __builtin_amdgcn_cvt_pkrtz(h2, h3));
    int pg = g8 ^ ((i & 15) << 1);
    *(uint2*)(hs8 + i * 272 + pg * 8) = pk2;
  }
  // stage f16 weights: 2048 16B-chunks = 128 rows x 16, 8 per thread
  const ush* Wb = type == 0 ? wqh : (type == 1 ? wkh : wvh);
#pragma unroll
  for (int p = 0; p < 8; ++p) {
    int cid = p * 256 + tid;
    int o = cid >> 4, ch = (cid & 15) << 3;
    *(uint4t*)&wol[o * 136 + ch] = *(const uint4t*)(Wb + (o << 7) + ch);
  }
  __syncthreads();

#define HS_FRAG(row, dc)                                     \
  __builtin_bit_cast(half8, *(const short8*)(hs8 + (row) * 272 + \
      (((((dc)*4 + quad)) ^ ((row)&15)) << 4)))
#define W_FRAG(o, dc)                                         \
  __builtin_bit_cast(half8, *(const short8*)&wol[(o)*136 + (dc)*32 + quad * 8])

  if (type < 2) {
    f32x4 acc[8] = {};
    int hrow = w * 16 + ln15;
#pragma unroll
    for (int dc = 0; dc < 4; ++dc) {
      half8 af = HS_FRAG(hrow, dc);
#pragma unroll
      for (int nb = 0; nb < 8; ++nb) {
        half8 bf = W_FRAG(nb * 16 + ln15, dc);
        acc[nb] = __builtin_amdgcn_mfma_f32_16x16x32_f16(af, bf, acc[nb], 0, 0, 0);
      }
    }
    const float* bias = type == 0 ? bq : bk;
    char* dst8 = type == 0 ? Qt8 : Kt8;
    __syncthreads();  // hs reads done; reuse as bounce [i 64][o 128] pitch 144
#pragma unroll
    for (int nb = 0; nb < 8; ++nb) {
      int o = nb * 16 + ln15;
      float bi = bias[o];
      float v0 = acc[nb][0] + bi, v1 = acc[nb][1] + bi;
      float v2 = acc[nb][2] + bi, v3 = acc[nb][3] + bi;
      if (type == 0) {
        v0 *= 0.12751742f; v1 *= 0.12751742f;  // log2(e)/sqrt(128)
        v2 *= 0.12751742f; v3 *= 0.12751742f;
      }
      unsigned u = (unsigned)__builtin_amdgcn_cvt_pk_fp8_f32(v0, v1, 0, false);
      u = (unsigned)__builtin_amdgcn_cvt_pk_fp8_f32(v2, v3, (int)u, true);
      int rbase = (w * 16 + quad * 4) * 144 + o;
      hs8[rbase] = (char)(u & 0xffu);
      hs8[rbase + 144] = (char)((u >> 8) & 0xffu);
      hs8[rbase + 288] = (char)((u >> 16) & 0xffu);
      hs8[rbase + 432] = (char)(u >> 24);
    }
    __syncthreads();
    int i = tid >> 2, seg = tid & 3;
    uint4 d0 = *(const uint4*)(hs8 + i * 144 + seg * 32);
    uint4 d1 = *(const uint4*)(hs8 + i * 144 + seg * 32 + 16);
    char* drow = dst8 + (((size_t)((b << 12) + i0 + i)) << 7) + seg * 32;
    *(uint4*)drow = d0;
    *(uint4*)(drow + 16) = d1;
  } else {
    f32x4 acc[8] = {};
    int hrow = w * 16 + ln15;
#pragma unroll
    for (int dc = 0; dc < 4; ++dc) {
      half8 bf = HS_FRAG(hrow, dc);
#pragma unroll
      for (int mb = 0; mb < 8; ++mb) {
        half8 af = W_FRAG(mb * 16 + ln15, dc);
        acc[mb] = __builtin_amdgcn_mfma_f32_16x16x32_f16(af, bf, acc[mb], 0, 0, 0);
      }
    }
#pragma unroll
    for (int mb = 0; mb < 8; ++mb) {
#pragma unroll
      for (int r = 0; r < 4; ++r) {
        int o = mb * 16 + quad * 4 + r;
        float val = acc[mb][r] + bv[o];
        Vh[(((size_t)((b << 7) + o)) << 12) + i0 + w * 16 + ln15] = (_Float16)val;
      }
    }
  }
#undef HS_FRAG
#undef W_FRAG
}

// ---------------------------------------------------------------------------
// Kernel 3: flash attention, 4-way key split.  grid 512 = b(8) x qt(16) x
// ks(4); 4 waves, 64 q/wave; 32 key-tiles of 32.  v12 structure (K=128
// scaled MFMA S-phase); v20 epilogue packs O partials as fp8 (HW cvt).
// ---------------------------------------------------------------------------
__global__ __launch_bounds__(256, 2) void attn_kernel(
    const char* __restrict__ Qt8, const char* __restrict__ Kt8,
    const _Float16* __restrict__ Vh, char* __restrict__ po,
    float* __restrict__ lw) {
  __shared__ __align__(16) char ksb[2][4096];      // [j32][d128] fp8 swizzled
  __shared__ __align__(16) _Float16 vsb[2][4096];  // [d128][j32] f16 swizzled
  int bx = blockIdx.x;
  int b = bx & 7, qt = (bx >> 3) & 15, ksid = bx >> 7;
  int tid = threadIdx.x;
  int w = tid >> 6, lane = tid & 63, ln15 = lane & 15, quad = lane >> 4;
  int qbase = (qt << 8) + (w << 6);
  int j0 = ksid << 10;

  // Q fp8 fragments for K=128 MFMA (B-operand: col=i, k=quad*32+[0,32))
  int8v qf[4];
#pragma unroll
  for (int ih = 0; ih < 4; ++ih) {
    const char* qrow =
        Qt8 + (((size_t)((b << 12) + qbase + ih * 16 + ln15)) << 7) + quad * 32;
    V8U u;
    u.h[0] = *(const uint4t*)(qrow);
    u.h[1] = *(const uint4t*)(qrow + 16);
    qf[ih] = u.v;
  }

  // DMA source mappings (swizzle folded into per-lane source address)
  int kj = (w << 3) + (lane >> 3);
  int kh = (kj & 3) | (((kj >> 3) & 1) << 2);
  int kg = (lane & 7) ^ kh;
  const char* ksrc = Kt8 + (((size_t)((b << 12) + j0 + kj)) << 7) + (kg << 4);
  int d0r = (w << 5) + (lane >> 2);
  int d1r = d0r + 16;
  int vg0 = (lane & 3) ^ (((d0r >> 1) + (d0r >> 3)) & 3);
  int vg1 = (lane & 3) ^ (((d1r >> 1) + (d1r >> 3)) & 3);
  const _Float16* vsrc0 =
      Vh + (((size_t)((b << 7) + d0r)) << 12) + j0 + (vg0 << 3);
  const _Float16* vsrc1 =
      Vh + (((size_t)((b << 7) + d1r)) << 12) + j0 + (vg1 << 3);
  char* kdA = &ksb[0][0] + (w << 10);
  char* kdB = &ksb[1][0] + (w << 10);
  char* vdA0 = (char*)&vsb[0][0] + ((w * 2 + 0) << 10);
  char* vdA1 = (char*)&vsb[0][0] + ((w * 2 + 1) << 10);
  char* vdB0 = (char*)&vsb[1][0] + ((w * 2 + 0) << 10);
  char* vdB1 = (char*)&vsb[1][0] + ((w * 2 + 1) << 10);

  // stage tile 0 into buf 0
  async16(ksrc, kdA);
  async16(vsrc0, vdA0);
  async16(vsrc1, vdA1);
  __syncthreads();

  f32x4 O[4][8] = {};  // O^T: [ih(i)][nb(d-block)]
  float lsum[4] = {0.f, 0.f, 0.f, 0.f};
  const f32x4 SINIT = {-7.2134752f, -7.2134752f, -7.2134752f, -7.2134752f};
  // permuted K rows for the S A-operand + their (shared) group hash
  int r0 = ((ln15 >> 2) << 3) + (ln15 & 3), r1 = r0 + 4;
  int hr = (ln15 & 3) | (((ln15 >> 2) & 1) << 2);
  // swizzled byte offsets of the two 16B k-groups this lane needs (k=quad*32)
  int g0 = ((2 * quad) ^ hr) << 4;
  int g1 = ((2 * quad + 1) ^ hr) << 4;

  for (int jt = 0; jt < 32; ++jt) {
    int buf = jt & 1;
    if (jt + 1 < 32) {
      ksrc += 4096;
      vsrc0 += 32;
      vsrc1 += 32;
      if (buf == 0) {
        async16(ksrc, kdB);
        async16(vsrc0, vdB0);
        async16(vsrc1, vdB1);
      } else {
        async16(ksrc, kdA);
        async16(vsrc0, vdA0);
        async16(vsrc1, vdA1);
      }
    }
    const char* kb = &ksb[buf][0];
    const char* vb = (const char*)&vsb[buf][0];

    // S^T = K(permuted rows) . Q  -- one K=128 scaled MFMA per (ih, row-tile)
    V8U ka, kc;
    ka.h[0] = *(const uint4t*)(kb + r0 * 128 + g0);
    ka.h[1] = *(const uint4t*)(kb + r0 * 128 + g1);
    kc.h[0] = *(const uint4t*)(kb + r1 * 128 + g0);
    kc.h[1] = *(const uint4t*)(kb + r1 * 128 + g1);
    f32x4 S[4][2];
#pragma unroll
    for (int ih = 0; ih < 4; ++ih) {
      S[ih][0] = __builtin_amdgcn_mfma_scale_f32_16x16x128_f8f6f4(
          ka.v, qf[ih], SINIT, 0, 0, 0, 0x7F7F7F7F, 0, 0x7F7F7F7F);
      S[ih][1] = __builtin_amdgcn_mfma_scale_f32_16x16x128_f8f6f4(
          kc.v, qf[ih], SINIT, 0, 0, 0, 0x7F7F7F7F, 0, 0x7F7F7F7F);
    }

    // exp2 -> f16 via packed cvt words; tile0 regs = k 0..3, tile1 = k 4..7
    half8 pf[4];
#pragma unroll
    for (int ih = 0; ih < 4; ++ih) {
      float p0 = __builtin_amdgcn_exp2f(S[ih][0][0]);
      float p1 = __builtin_amdgcn_exp2f(S[ih][0][1]);
      float p2 = __builtin_amdgcn_exp2f(S[ih][0][2]);
      float p3 = __builtin_amdgcn_exp2f(S[ih][0][3]);
      float p4 = __builtin_amdgcn_exp2f(S[ih][1][0]);
      float p5 = __builtin_amdgcn_exp2f(S[ih][1][1]);
      float p6 = __builtin_amdgcn_exp2f(S[ih][1][2]);
      float p7 = __builtin_amdgcn_exp2f(S[ih][1][3]);
      lsum[ih] += ((p0 + p1) + (p2 + p3)) + ((p4 + p5) + (p6 + p7));
      uint4t pw;
      pw.x = __builtin_bit_cast(unsigned, __builtin_amdgcn_cvt_pkrtz(p0, p1));
      pw.y = __builtin_bit_cast(unsigned, __builtin_amdgcn_cvt_pkrtz(p2, p3));
      pw.z = __builtin_bit_cast(unsigned, __builtin_amdgcn_cvt_pkrtz(p4, p5));
      pw.w = __builtin_bit_cast(unsigned, __builtin_amdgcn_cvt_pkrtz(p6, p7));
      pf[ih] = __builtin_bit_cast(half8, pw);
    }
    // O^T += V . P   (f16 K=32 MFMA, 32/iter; V frag = one b128)
#pragma unroll
    for (int nb = 0; nb < 8; ++nb) {
      int d = nb * 16 + ln15;
      int sd = ((d >> 1) + (d >> 3)) & 3;
      half8 vf = *(const half8*)(vb + d * 64 + ((quad ^ sd) << 4));
#pragma unroll
      for (int ih = 0; ih < 4; ++ih)
        O[ih][nb] = __builtin_amdgcn_mfma_f32_16x16x32_f16(vf, pf[ih], O[ih][nb], 0, 0, 0);
    }
    __syncthreads();  // drains DMA + tile handoff
  }

  // epilogue: unnormalized partial O^T (fp8) -> po[ks][b][i][d], sums -> lw
#pragma unroll
  for (int ih = 0; ih < 4; ++ih) {
    float l = lsum[ih];
    l += __shfl_xor(l, 16);
    l += __shfl_xor(l, 32);
    if (quad == 0) lw[(ksid << 15) + (b << 12) + qbase + ih * 16 + ln15] = l;
    int i = qbase + ih * 16 + ln15;
    size_t rowb = (((size_t)((ksid * 8 + b)) << 12) + i) << 7;  // bytes
#pragma unroll
    for (int nb = 0; nb < 8; ++nb) {
      unsigned u = (unsigned)__builtin_amdgcn_cvt_pk_fp8_f32(
          O[ih][nb][0], O[ih][nb][1], 0, false);
      u = (unsigned)__builtin_amdgcn_cvt_pk_fp8_f32(
          O[ih][nb][2], O[ih][nb][3], (int)u, true);
      *(unsigned*)(po + rowb + nb * 16 + quad * 4) = u;
    }
  }
}

// ---------------------------------------------------------------------------
// Kernel 4: combine key-split partials + proj + bias + residual.
// grid 1024 = oh(2) x b(8) x itile(64).  v20: po fp8, decoded with HW
// cvt_pk_f32_fp8, combined in f32, packed f16 for the MFMA.
// ---------------------------------------------------------------------------
__global__ __launch_bounds__(256) void proj_kernel(
    const float* __restrict__ x, const char* __restrict__ po,
    const float* __restrict__ lw, const ush* __restrict__ wobh,
    const float* __restrict__ bo, float* __restrict__ out) {
  int bx = blockIdx.x;
  int oh = bx & 1;  // o-half: mb base = oh*4
  int bi = bx >> 1;
  int b = bi >> 6, i0 = (bi & 63) << 6;
  int tid = threadIdx.x;
  int w = tid >> 6, lane = tid & 63, ln15 = lane & 15, quad = lane >> 4;
  int i = i0 + w * 16 + ln15;
  float rl = 0.f;
#pragma unroll
  for (int s = 0; s < 4; ++s) rl += lw[(s << 15) + (b << 12) + i];
  float rinv = 1.f / rl;

  f32x4 acc[4] = {};
#pragma unroll
  for (int dc = 0; dc < 4; ++dc) {
    size_t base = ((size_t)i << 7) + dc * 32 + quad * 8;
    float vs0 = 0.f, vs1 = 0.f, vs2 = 0.f, vs3 = 0.f;
    float vs4 = 0.f, vs5 = 0.f, vs6 = 0.f, vs7 = 0.f;
#pragma unroll
    for (int s = 0; s < 4; ++s) {
      ull pv = *(const ull*)(po + (((size_t)(s * 8 + b)) << 19) + base);
      int lo = (int)(unsigned)pv, hi = (int)(unsigned)(pv >> 32);
      f32x2 a0 = __builtin_amdgcn_cvt_pk_f32_fp8(lo, false);
      f32x2 a1 = __builtin_amdgcn_cvt_pk_f32_fp8(lo, true);
      f32x2 a2 = __builtin_amdgcn_cvt_pk_f32_fp8(hi, false);
      f32x2 a3 = __builtin_amdgcn_cvt_pk_f32_fp8(hi, true);
      vs0 += a0.x; vs1 += a0.y; vs2 += a1.x; vs3 += a1.y;
      vs4 += a2.x; vs5 += a2.y; vs6 += a3.x; vs7 += a3.y;
    }
    uint4t pw;
    pw.x = __builtin_bit_cast(unsigned,
                              __builtin_amdgcn_cvt_pkrtz(vs0 * rinv, vs1 * rinv));
    pw.y = __builtin_bit_cast(unsigned,
                              __builtin_amdgcn_cvt_pkrtz(vs2 * rinv, vs3 * rinv));
    pw.z = __builtin_bit_cast(unsigned,
                              __builtin_amdgcn_cvt_pkrtz(vs4 * rinv, vs5 * rinv));
    pw.w = __builtin_bit_cast(unsigned,
                              __builtin_amdgcn_cvt_pkrtz(vs6 * rinv, vs7 * rinv));
    half8 bfv = __builtin_bit_cast(half8, pw);
#pragma unroll
    for (int mb = 0; mb < 4; ++mb) {
      half8 af = *(const half8*)&wobh[(((oh * 4 + mb) * 16 + ln15) << 7) +
                                      dc * 32 + quad * 8];
      acc[mb] = __builtin_amdgcn_mfma_f32_16x16x32_f16(af, bfv, acc[mb], 0, 0, 0);
    }
  }
#pragma unroll
  for (int mb = 0; mb < 4; ++mb) {
#pragma unroll
    for (int r = 0; r < 4; ++r) {
      int o = (oh * 4 + mb) * 16 + quad * 4 + r;
      size_t idx = (((size_t)(b << 7) + o) << 12) + i;
      out[idx] = x[idx] + acc[mb][r] + bo[o];
    }
  }
}

// ---------------------------------------------------------------------------
extern "C" void kernel_launch(void* const* d_in, const int* in_sizes, int n_in,
                              void* d_out, int out_size, void* d_ws,
                              size_t ws_size, hipStream_t stream) {
  const float* x = (const float*)d_in[0];
  const float* gamma = (const float*)d_in[1];
  const float* beta = (const float*)d_in[2];
  const float* wq = (const float*)d_in[3];
  const float* bq = (const float*)d_in[4];
  const float* wk = (const float*)d_in[5];
  const float* bk = (const float*)d_in[6];
  const float* wv = (const float*)d_in[7];
  const float* bv = (const float*)d_in[8];
  const float* wo = (const float*)d_in[9];
  const float* bo = (const float*)d_in[10];
  float* out = (float*)d_out;

  const size_t NE = (size_t)8 * 4096 * 128;  // 4M elements
  char* Qt8 = (char*)d_ws;               // fp8 Q^T [b][i][d]   (4MB)
  char* Kt8 = Qt8 + NE;                  // fp8 K^T [b][j][d]   (4MB)
  _Float16* Vh = (_Float16*)(Kt8 + NE);  // f16 V [b][d][j]     (8MB)
  char* po = (char*)(Vh + NE);           // fp8 partial O [4][b][i][d] (16MB)
  float* lwp = (float*)(po + 4 * NE);    // f32 partial l [4][b][i] (512KB)
  float* scale_c = lwp + 4 * 32768;
  float* shift_c = scale_c + 1024;
  ush* wobh = (ush*)(shift_c + 1024);    // f16 wo [o][c] (32KB)
  ush* wqh = wobh + 16384;               // f16 wq [o][c] (32KB)
  ush* wkh = wqh + 16384;                // f16 wk
  ush* wvh = wkh + 16384;                // f16 wv

  gn_stats_kernel<<<256, 256, 0, stream>>>(x, gamma, beta, wo, wq, wk, wv,
                                           scale_c, shift_c, wobh, wqh, wkh,
                                           wvh);
  qkv_kernel<<<1536, 256, 0, stream>>>(x, scale_c, shift_c, wqh, wkh, wvh, bq,
                                       bk, bv, Qt8, Kt8, Vh);
  attn_kernel<<<512, 256, 0, stream>>>(Qt8, Kt8, Vh, po, lwp);
  proj_kernel<<<1024, 256, 0, stream>>>(x, po, lwp, wobh, bo, out);
}